// Round 1
// baseline (112.691 us; speedup 1.0000x reference)
//
#include <hip/hip_runtime.h>

// Problem constants (fixed by setup_inputs in the reference)
constexpr int BATCH = 16;
constexpr int M = 8400;     // num predictions
constexpr int J = 64;       // num gt boxes
constexpr int C = 80;       // num classes
constexpr int BLOCK = 256;
constexpr int C4 = C / 4;   // 20 float4 slots per row

__global__ __launch_bounds__(BLOCK) void pocoo_loss_kernel(
    const float* __restrict__ bfinal,   // [B,M,4]  (cx,cy,w,h)
    const float* __restrict__ scores,   // [B,M,C]
    const float* __restrict__ gtb,      // [B,J,4]
    const float* __restrict__ gtl,      // [B,J,C]
    const int* __restrict__ Hp,
    const int* __restrict__ Wp,
    float* __restrict__ out)
{
    __shared__ float s_gx1[J], s_gy1[J], s_gx2[J], s_gy2[J];
    __shared__ float s_ga[J], s_gw[J], s_gh[J];
    __shared__ __align__(16) float s_lab[J * C];   // 20 KB
    __shared__ float s_wpos[BLOCK];
    __shared__ int   s_bj[BLOCK];
    __shared__ float s_red[BLOCK / 64];

    const int b   = blockIdx.y;
    const int m0  = blockIdx.x * BLOCK;
    const int tid = threadIdx.x;

    // ---- stage GT boxes (corners + area) ----
    if (tid < J) {
        const float* g = gtb + ((size_t)b * J + tid) * 4;
        float cx = g[0], cy = g[1], w = g[2], h = g[3];
        float x1 = cx - w * 0.5f, y1 = cy - h * 0.5f;
        float x2 = cx + w * 0.5f, y2 = cy + h * 0.5f;
        s_gx1[tid] = x1; s_gy1[tid] = y1;
        s_gx2[tid] = x2; s_gy2[tid] = y2;
        s_ga[tid]  = (x2 - x1) * (y2 - y1);
        s_gw[tid]  = w; s_gh[tid] = h;
    }
    // ---- stage GT labels (coalesced float4) ----
    {
        const float4* gl4 = (const float4*)(gtl + (size_t)b * J * C);
        float4* sl4 = (float4*)s_lab;
        #pragma unroll
        for (int i = tid; i < J * C / 4; i += BLOCK) sl4[i] = gl4[i];
    }
    __syncthreads();

    // ---- Phase A: per-row IoU argmax -> w_pos, best_j ----
    const int m = m0 + tid;
    float wpos = 0.0f;
    int bj = 0;
    if (m < M) {
        const float* p = bfinal + ((size_t)b * M + m) * 4;
        float cx = p[0], cy = p[1], w = p[2], h = p[3];
        float px1 = cx - w * 0.5f, py1 = cy - h * 0.5f;
        float px2 = cx + w * 0.5f, py2 = cy + h * 0.5f;
        float parea = (px2 - px1) * (py2 - py1);
        float best = -1.0f;
        #pragma unroll 4
        for (int j = 0; j < J; ++j) {
            float iw = fminf(px2, s_gx2[j]) - fmaxf(px1, s_gx1[j]);
            float ih = fminf(py2, s_gy2[j]) - fmaxf(py1, s_gy1[j]);
            iw = fmaxf(iw, 0.0f);
            ih = fmaxf(ih, 0.0f);
            float inter = iw * ih;
            float uni = parea + s_ga[j] - inter;
            float iou = inter / (uni + 1e-6f);
            if (iou > best) { best = iou; bj = j; }   // strict > == first-max (argmax)
        }
        if (best > 0.5f) {
            float Wf = (float)(*Wp);
            float Hf = (float)(*Hp);
            float sf = sqrtf(1.0f - sqrtf((s_gw[bj] / Wf) * (s_gh[bj] / Hf)));  // ALPHA=0.5
            wpos = sf + 1.0f;
        }
    }
    s_wpos[tid] = wpos;
    s_bj[tid]   = bj;
    __syncthreads();

    // ---- Phase B: coalesced BCE over the block's [rows x C] score slab ----
    const int rows   = min(M - m0, BLOCK);
    const int nslots = rows * C4;          // float4 slots
    const float4* sc4 = (const float4*)(scores + ((size_t)b * M + m0) * C);

    float acc = 0.0f;
    for (int s = tid; s < nslots; s += BLOCK) {
        int ml = s / C4;                   // local row
        int c4 = s - ml * C4;              // float4 index within row
        float4 p4 = sc4[s];
        float wp = s_wpos[ml];
        const float4 y4 = *(const float4*)&s_lab[s_bj[ml] * C + c4 * 4];

        float pv[4] = {p4.x, p4.y, p4.z, p4.w};
        float yv[4] = {y4.x, y4.y, y4.z, y4.w};
        #pragma unroll
        for (int k = 0; k < 4; ++k) {
            float p   = pv[k];
            float l1p = fmaxf(__logf(1.0f - p), -100.0f);
            if (wp > 0.0f) {
                float lp = fmaxf(__logf(p), -100.0f);
                float y  = yv[k];
                acc += -(y * lp + (1.0f - y) * l1p) * wp;
            } else {
                acc += -l1p * p * p;       // BCE(p,0) * p^2
            }
        }
    }

    // ---- reduction: wave shuffle -> LDS -> atomic ----
    #pragma unroll
    for (int off = 32; off > 0; off >>= 1) acc += __shfl_down(acc, off, 64);
    const int lane = tid & 63;
    const int wid  = tid >> 6;
    if (lane == 0) s_red[wid] = acc;
    __syncthreads();
    if (tid == 0) {
        float bsum = 0.0f;
        #pragma unroll
        for (int wv = 0; wv < BLOCK / 64; ++wv) bsum += s_red[wv];
        atomicAdd(out, bsum * (1.0f / (float)BATCH));
    }
}

extern "C" void kernel_launch(void* const* d_in, const int* in_sizes, int n_in,
                              void* d_out, int out_size, void* d_ws, size_t ws_size,
                              hipStream_t stream) {
    const float* bfinal = (const float*)d_in[0];
    const float* scores = (const float*)d_in[1];
    const float* gtb    = (const float*)d_in[2];
    const float* gtl    = (const float*)d_in[3];
    const int*   Hp     = (const int*)d_in[4];
    const int*   Wp     = (const int*)d_in[5];
    float* out = (float*)d_out;

    // d_out is re-poisoned to 0xAA before every timed replay -> zero it on-stream.
    hipMemsetAsync(out, 0, sizeof(float), stream);

    dim3 grid((M + BLOCK - 1) / BLOCK, BATCH);
    pocoo_loss_kernel<<<grid, BLOCK, 0, stream>>>(bfinal, scores, gtb, gtl, Hp, Wp, out);
}

// Round 2
// 109.860 us; speedup vs baseline: 1.0258x; 1.0258x over previous
//
#include <hip/hip_runtime.h>

// Problem constants (fixed by setup_inputs in the reference)
constexpr int BATCH = 16;
constexpr int M = 8400;     // num predictions
constexpr int J = 64;       // num gt boxes
constexpr int C = 80;       // num classes
constexpr int BLOCK = 256;
constexpr int C4 = C / 4;   // 20 float4 slots per row
constexpr int GRID_X = (M + BLOCK - 1) / BLOCK;   // 33
constexpr int NPART = GRID_X * BATCH;             // 528 block partials

__global__ __launch_bounds__(BLOCK) void pocoo_loss_kernel(
    const float* __restrict__ bfinal,   // [B,M,4]  (cx,cy,w,h)
    const float* __restrict__ scores,   // [B,M,C]
    const float* __restrict__ gtb,      // [B,J,4]
    const float* __restrict__ gtl,      // [B,J,C]
    const int* __restrict__ Hp,
    const int* __restrict__ Wp,
    float* __restrict__ partials)       // [NPART]
{
    __shared__ float s_gx1[J], s_gy1[J], s_gx2[J], s_gy2[J];
    __shared__ float s_ga[J], s_gw[J], s_gh[J];
    __shared__ __align__(16) float s_lab[J * C];   // 20 KB
    __shared__ float s_wpos[BLOCK];
    __shared__ int   s_bj[BLOCK];
    __shared__ float s_red[BLOCK / 64];

    const int b   = blockIdx.y;
    const int m0  = blockIdx.x * BLOCK;
    const int tid = threadIdx.x;

    // ---- stage GT boxes (corners + area) ----
    if (tid < J) {
        const float* g = gtb + ((size_t)b * J + tid) * 4;
        float cx = g[0], cy = g[1], w = g[2], h = g[3];
        float x1 = cx - w * 0.5f, y1 = cy - h * 0.5f;
        float x2 = cx + w * 0.5f, y2 = cy + h * 0.5f;
        s_gx1[tid] = x1; s_gy1[tid] = y1;
        s_gx2[tid] = x2; s_gy2[tid] = y2;
        s_ga[tid]  = (x2 - x1) * (y2 - y1);
        s_gw[tid]  = w; s_gh[tid] = h;
    }
    // ---- stage GT labels (coalesced float4) ----
    {
        const float4* gl4 = (const float4*)(gtl + (size_t)b * J * C);
        float4* sl4 = (float4*)s_lab;
        #pragma unroll
        for (int i = tid; i < J * C / 4; i += BLOCK) sl4[i] = gl4[i];
    }
    __syncthreads();

    // ---- Phase A: per-row IoU argmax -> w_pos, best_j ----
    const int m = m0 + tid;
    float wpos = 0.0f;
    int bj = 0;
    if (m < M) {
        const float* p = bfinal + ((size_t)b * M + m) * 4;
        float cx = p[0], cy = p[1], w = p[2], h = p[3];
        float px1 = cx - w * 0.5f, py1 = cy - h * 0.5f;
        float px2 = cx + w * 0.5f, py2 = cy + h * 0.5f;
        float parea = (px2 - px1) * (py2 - py1);
        float best = -1.0f;
        #pragma unroll 4
        for (int j = 0; j < J; ++j) {
            float iw = fminf(px2, s_gx2[j]) - fmaxf(px1, s_gx1[j]);
            float ih = fminf(py2, s_gy2[j]) - fmaxf(py1, s_gy1[j]);
            iw = fmaxf(iw, 0.0f);
            ih = fmaxf(ih, 0.0f);
            float inter = iw * ih;
            float uni = parea + s_ga[j] - inter;
            float iou = inter / (uni + 1e-6f);
            if (iou > best) { best = iou; bj = j; }   // strict > == first-max (argmax)
        }
        if (best > 0.5f) {
            float Wf = (float)(*Wp);
            float Hf = (float)(*Hp);
            float sf = sqrtf(1.0f - sqrtf((s_gw[bj] / Wf) * (s_gh[bj] / Hf)));  // ALPHA=0.5
            wpos = sf + 1.0f;
        }
    }
    s_wpos[tid] = wpos;
    s_bj[tid]   = bj;
    __syncthreads();

    // ---- Phase B: coalesced BCE over the block's [rows x C] score slab ----
    const int rows   = min(M - m0, BLOCK);
    const int nslots = rows * C4;          // float4 slots
    const float4* sc4 = (const float4*)(scores + ((size_t)b * M + m0) * C);

    float acc = 0.0f;
    for (int s = tid; s < nslots; s += BLOCK) {
        int ml = s / C4;                   // local row
        int c4 = s - ml * C4;              // float4 index within row
        float4 p4 = sc4[s];
        float wp = s_wpos[ml];
        const float4 y4 = *(const float4*)&s_lab[s_bj[ml] * C + c4 * 4];

        float pv[4] = {p4.x, p4.y, p4.z, p4.w};
        float yv[4] = {y4.x, y4.y, y4.z, y4.w};
        #pragma unroll
        for (int k = 0; k < 4; ++k) {
            float p   = pv[k];
            float l1p = fmaxf(__logf(1.0f - p), -100.0f);
            if (wp > 0.0f) {
                float lp = fmaxf(__logf(p), -100.0f);
                float y  = yv[k];
                acc += -(y * lp + (1.0f - y) * l1p) * wp;
            } else {
                acc += -l1p * p * p;       // BCE(p,0) * p^2
            }
        }
    }

    // ---- reduction: wave shuffle -> LDS -> one plain store per block ----
    #pragma unroll
    for (int off = 32; off > 0; off >>= 1) acc += __shfl_down(acc, off, 64);
    const int lane = tid & 63;
    const int wid  = tid >> 6;
    if (lane == 0) s_red[wid] = acc;
    __syncthreads();
    if (tid == 0) {
        float bsum = 0.0f;
        #pragma unroll
        for (int wv = 0; wv < BLOCK / 64; ++wv) bsum += s_red[wv];
        partials[blockIdx.y * gridDim.x + blockIdx.x] = bsum;   // plain store, no init needed
    }
}

__global__ __launch_bounds__(256) void pocoo_reduce_kernel(
    const float* __restrict__ partials, float* __restrict__ out)
{
    __shared__ float s_red[4];
    const int tid = threadIdx.x;
    float acc = 0.0f;
    for (int i = tid; i < NPART; i += 256) acc += partials[i];
    #pragma unroll
    for (int off = 32; off > 0; off >>= 1) acc += __shfl_down(acc, off, 64);
    const int lane = tid & 63;
    const int wid  = tid >> 6;
    if (lane == 0) s_red[wid] = acc;
    __syncthreads();
    if (tid == 0) {
        float t = s_red[0] + s_red[1] + s_red[2] + s_red[3];
        out[0] = t * (1.0f / (float)BATCH);
    }
}

extern "C" void kernel_launch(void* const* d_in, const int* in_sizes, int n_in,
                              void* d_out, int out_size, void* d_ws, size_t ws_size,
                              hipStream_t stream) {
    const float* bfinal = (const float*)d_in[0];
    const float* scores = (const float*)d_in[1];
    const float* gtb    = (const float*)d_in[2];
    const float* gtl    = (const float*)d_in[3];
    const int*   Hp     = (const int*)d_in[4];
    const int*   Wp     = (const int*)d_in[5];
    float* out      = (float*)d_out;
    float* partials = (float*)d_ws;

    dim3 grid(GRID_X, BATCH);
    pocoo_loss_kernel<<<grid, BLOCK, 0, stream>>>(bfinal, scores, gtb, gtl, Hp, Wp, partials);
    pocoo_reduce_kernel<<<1, 256, 0, stream>>>(partials, out);
}